// Round 11
// baseline (306.285 us; speedup 1.0000x reference)
//
#include <hip/hip_runtime.h>

#define EMBED 768
#define HEADS 12
#define HDIM 64
#define MLP_DIM 3072
#define BATCH 4
#define SEQ 1024
#define ROWS (BATCH*SEQ)
#define LN_EPS 1e-5f

typedef __bf16 bf16x8 __attribute__((ext_vector_type(8)));
typedef float f32x4 __attribute__((ext_vector_type(4)));

__device__ __forceinline__ float bf2f(unsigned short h) {
    unsigned u = ((unsigned)h) << 16;
    return __builtin_bit_cast(float, u);
}
__device__ __forceinline__ unsigned short f2bf(float f) {
    unsigned u = __builtin_bit_cast(unsigned, f);
    unsigned r = (u + 0x7fffu + ((u >> 16) & 1u)) >> 16;
    return (unsigned short)r;
}

// async global->LDS, 16B per lane (wave-uniform base + lane*16 contract).
__device__ __forceinline__ void async_load16(const unsigned short* g, unsigned short* l) {
    __builtin_amdgcn_global_load_lds(
        (const __attribute__((address_space(1))) unsigned int*)g,
        (__attribute__((address_space(3))) unsigned int*)l,
        16, 0, 0);
}

// ---- classify the six 768-vectors by VALUE and copy to canonical slots ----
__global__ void sort_vecs(const float* a0, const float* a1, const float* a2,
                          const float* a3, const float* a4, const float* a5,
                          float* g1, float* be1, float* bo,
                          float* g2, float* be2, float* bb2)
{
    const float* src[6] = {a0, a1, a2, a3, a4, a5};
    float* gdst[2] = {g1, g2};
    float* bdst[4] = {be1, bo, be2, bb2};
    float* dst[6];
    int gi = 0, bi = 0;
    for (int t = 0; t < 6; t++) {
        bool ones = (src[t][0] == 1.0f);
        if (ones) dst[t] = (gi < 2) ? gdst[gi++] : bdst[bi++];
        else      dst[t] = (bi < 4) ? bdst[bi++] : gdst[gi++];
    }
    int t = threadIdx.x;   // 768 threads
    for (int k = 0; k < 6; k++) dst[k][t] = src[k][t];
}

// ---- all 4 weight transposes (f32 -> bf16 [N,K]) in ONE launch -------------
__global__ void transpose_weights(const float* __restrict__ wqkv,
                                  const float* __restrict__ wout,
                                  const float* __restrict__ w1,
                                  const float* __restrict__ w2,
                                  unsigned short* __restrict__ wqkvT,
                                  unsigned short* __restrict__ woutT,
                                  unsigned short* __restrict__ w1T,
                                  unsigned short* __restrict__ w2T)
{
    __shared__ unsigned short t[32][33];
    int fb = blockIdx.x;
    const float* src; unsigned short* dst; int gx, ild, old;
    if (fb < 1728)      { src = wqkv; dst = wqkvT; gx = 72; ild = 2304; old = 768; }
    else if (fb < 2304) { fb -= 1728; src = wout; dst = woutT; gx = 24; ild = 768;  old = 768; }
    else if (fb < 4608) { fb -= 2304; src = w1;   dst = w1T;   gx = 96; ild = 3072; old = 768; }
    else                { fb -= 4608; src = w2;   dst = w2T;   gx = 24; ild = 768;  old = 3072; }
    const int j0 = (fb % gx) * 32, i0 = (fb / gx) * 32;
#pragma unroll
    for (int r = 0; r < 4; r++)
        t[threadIdx.y + r*8][threadIdx.x] =
            f2bf(src[(long)(i0 + threadIdx.y + r*8) * ild + (j0 + threadIdx.x)]);
    __syncthreads();
#pragma unroll
    for (int r = 0; r < 4; r++)
        dst[(long)(j0 + threadIdx.y + r*8) * old + (i0 + threadIdx.x)] =
            t[threadIdx.x][threadIdx.y + r*8];
}

// ---- tiled transpose (bf16 path, used for vT) ------------------------------
__global__ void transpose_any(const void* __restrict__ in,
                              unsigned short* __restrict__ out,
                              int ild, int old,
                              long in_zo, long in_zi, long out_zo, long out_zi,
                              int zdiv, int in_is_f32)
{
    __shared__ unsigned short t[32][33];
    const int z = blockIdx.z;
    const long ib = (long)(z / zdiv) * in_zo  + (long)(z % zdiv) * in_zi;
    const long ob = (long)(z / zdiv) * out_zo + (long)(z % zdiv) * out_zi;
    const int j0 = blockIdx.x * 32, i0 = blockIdx.y * 32;
#pragma unroll
    for (int r = 0; r < 4; r++) {
        long idx = ib + (long)(i0 + threadIdx.y + r*8) * ild + (j0 + threadIdx.x);
        t[threadIdx.y + r*8][threadIdx.x] =
            in_is_f32 ? f2bf(((const float*)in)[idx]) : ((const unsigned short*)in)[idx];
    }
    __syncthreads();
#pragma unroll
    for (int r = 0; r < 4; r++)
        out[ob + (long)(j0 + threadIdx.y + r*8) * old + (i0 + threadIdx.x)] =
            t[threadIdx.x][threadIdx.y + r*8];
}

// ---------------- LayerNorm: f32 in, f32 gamma/beta -> bf16 out -------------
__global__ void ln_kernel(const float* __restrict__ xin,
                          const float* __restrict__ g,
                          const float* __restrict__ b,
                          unsigned short* __restrict__ out)
{
    const int row = blockIdx.x;
    const int tid = threadIdx.x;
    const long base = (long)row * EMBED;
    float v[3];
#pragma unroll
    for (int i = 0; i < 3; i++) v[i] = xin[base + tid + i * 256];
    float s = v[0] + v[1] + v[2];
    float s2 = v[0]*v[0] + v[1]*v[1] + v[2]*v[2];
    for (int off = 32; off; off >>= 1) { s += __shfl_down(s, off); s2 += __shfl_down(s2, off); }
    __shared__ float ps[4], ps2[4];
    int w = tid >> 6, l = tid & 63;
    if (l == 0) { ps[w] = s; ps2[w] = s2; }
    __syncthreads();
    float ts  = ps[0] + ps[1] + ps[2] + ps[3];
    float ts2 = ps2[0] + ps2[1] + ps2[2] + ps2[3];
    float mu = ts * (1.0f / EMBED);
    float var = ts2 * (1.0f / EMBED) - mu * mu;
    float rs = rsqrtf(var + LN_EPS);
#pragma unroll
    for (int i = 0; i < 3; i++) {
        int c = tid + i * 256;
        out[base + c] = f2bf((v[i] - mu) * rs * g[c] + b[c]);
    }
}

// --------- flash attention v6: swizzled LDS + MAX-FREE softmax --------------
__global__ __launch_bounds__(256) void flash_attn(
    const unsigned short* __restrict__ qkv,
    const unsigned short* __restrict__ vT,
    unsigned short* __restrict__ attn)
{
    __shared__ __align__(16) unsigned short QPs[64 * 64];     // Q staging, then P
    __shared__ __align__(16) unsigned short Ks[2][64 * 64];
    __shared__ __align__(16) unsigned short Vs[2][64 * 64];

    const int tid = threadIdx.x;
    const int wave = tid >> 6, lane = tid & 63;
    const int quad = lane >> 4, lr = lane & 15;
    const int q0 = blockIdx.x * 64;
    const int bh = blockIdx.y;
    const int b = bh / HEADS, h = bh % HEADS;

    const unsigned short* qb = qkv + (size_t)b * SEQ * 3 * EMBED + h * HDIM;
    const unsigned short* kb = qb + EMBED;
    const unsigned short* vb = vT + (size_t)bh * HDIM * SEQ;

#pragma unroll
    for (int cb = 0; cb < 512; cb += 256) {
        int p = cb + tid, r = p >> 3, cc = (p & 7) ^ (r & 7);
        async_load16(qb + (long)(q0 + r) * (3 * EMBED) + cc * 8, QPs + p * 8);
        async_load16(kb + (long)r * (3 * EMBED) + cc * 8, Ks[0] + p * 8);
        async_load16(vb + (long)r * SEQ + cc * 8, Vs[0] + p * 8);
    }
    __syncthreads();

    bf16x8 aq[2];
#pragma unroll
    for (int s = 0; s < 2; s++) {
        int row = wave * 16 + lr;
        aq[s] = *(const bf16x8*)&QPs[(row * 8 + ((s * 4 + quad) ^ (row & 7))) * 8];
    }

    f32x4 oacc[4];
#pragma unroll
    for (int j = 0; j < 4; j++) oacc[j] = (f32x4){0.f, 0.f, 0.f, 0.f};
    float lpart[4] = {0.f, 0.f, 0.f, 0.f};

    int cur = 0;
    for (int t = 0; t < SEQ / 64; t++) {
        bool pf = (t + 1 < SEQ / 64);
        if (pf) {
            int kv0 = (t + 1) * 64;
#pragma unroll
            for (int cb = 0; cb < 512; cb += 256) {
                int p = cb + tid, r = p >> 3, cc = (p & 7) ^ (r & 7);
                async_load16(kb + (long)(kv0 + r) * (3 * EMBED) + cc * 8, Ks[cur ^ 1] + p * 8);
                async_load16(vb + (long)r * SEQ + kv0 + cc * 8, Vs[cur ^ 1] + p * 8);
            }
        }
        f32x4 sacc[4];
#pragma unroll
        for (int j = 0; j < 4; j++) sacc[j] = (f32x4){0.f, 0.f, 0.f, 0.f};
#pragma unroll
        for (int s = 0; s < 2; s++)
#pragma unroll
            for (int j = 0; j < 4; j++) {
                int row = j * 16 + lr;
                bf16x8 bk = *(const bf16x8*)&Ks[cur][(row * 8 + ((s * 4 + quad) ^ (lr & 7))) * 8];
                sacc[j] = __builtin_amdgcn_mfma_f32_16x16x32_bf16(aq[s], bk, sacc[j], 0, 0, 0);
            }
#pragma unroll
        for (int j = 0; j < 4; j++)
#pragma unroll
            for (int r = 0; r < 4; r++) {
                float e = __expf(sacc[j][r] * 0.125f);
                lpart[r] += e;
                int row = wave * 16 + quad * 4 + r;
                int cc = (2 * j + (lr >> 3)) ^ (row & 7);
                QPs[(row * 8 + cc) * 8 + (lr & 7)] = f2bf(e);
            }
#pragma unroll
        for (int s = 0; s < 2; s++) {
            int prow = wave * 16 + lr;
            bf16x8 ap = *(const bf16x8*)&QPs[(prow * 8 + ((s * 4 + quad) ^ (prow & 7))) * 8];
#pragma unroll
            for (int j = 0; j < 4; j++) {
                int vrow = j * 16 + lr;
                bf16x8 bv = *(const bf16x8*)&Vs[cur][(vrow * 8 + ((s * 4 + quad) ^ (lr & 7))) * 8];
                oacc[j] = __builtin_amdgcn_mfma_f32_16x16x32_bf16(ap, bv, oacc[j], 0, 0, 0);
            }
        }
        __syncthreads();
        cur ^= 1;
    }
#pragma unroll
    for (int off = 1; off < 16; off <<= 1)
#pragma unroll
        for (int r = 0; r < 4; r++) lpart[r] += __shfl_xor(lpart[r], off);
#pragma unroll
    for (int j = 0; j < 4; j++)
#pragma unroll
        for (int r = 0; r < 4; r++) {
            int row = q0 + wave * 16 + quad * 4 + r;
            attn[(size_t)(b * SEQ + row) * EMBED + h * HDIM + j * 16 + lr] =
                f2bf(oacc[j][r] / lpart[r]);
        }
}

// ------- gemm_bt0: R10-exact. 128x128, BK=32, linear LDS, dbuf, drain,
// 512 thr / 8 waves, 2D XCD swizzle (4y x 2x -> per-XCD panels fit 4MB L2).
__global__ __launch_bounds__(512) void gemm_bt0(
    const unsigned short* __restrict__ A, int lda,
    const unsigned short* __restrict__ Bt, int ldb,
    int Kdim,
    const float* __restrict__ bias,
    unsigned short* __restrict__ Cb,
    int ldc, int gelu_flag)
{
    constexpr int BK = 32;
    __shared__ __align__(16) unsigned short As[2][128 * BK];
    __shared__ __align__(16) unsigned short Bs[2][128 * BK];

    const int tid = threadIdx.x;      // 0..511
    const int wave = tid >> 6;        // 0..7
    const int lane = tid & 63;
    const int quad = lane >> 4;
    const int lrow = lane & 15;
    const int wr = wave >> 2;         // 0..1 : M 64-half
    const int wc = wave & 3;          // 0..3 : N 32-quarter

    int bx = blockIdx.x, by = blockIdx.y;
    {   // 2D XCD swizzle: 4 y-groups x 2 x-groups of XCDs
        int flat = by * gridDim.x + bx;
        int xcd = flat & 7, seq = flat >> 3;
        int gxh = gridDim.x >> 1;   // region width  (x)
        int gyq = gridDim.y >> 2;   // region height (y)
        by = (xcd & 3) * gyq + seq / gxh;
        bx = (xcd >> 2) * gxh + seq % gxh;
    }
    const int m0 = by * 128;
    const int n0 = bx * 128;

    f32x4 acc[4][2];
#pragma unroll
    for (int i = 0; i < 4; i++)
#pragma unroll
        for (int j = 0; j < 2; j++) acc[i][j] = (f32x4){0.f, 0.f, 0.f, 0.f};

    const int srow = tid >> 2;
    const int scol = (tid & 3) * 8;

    auto stage = [&](int k0, int bsel) {
        async_load16(A  + (long)(m0 + srow) * lda + k0 + scol,
                     (unsigned short*)As[bsel] + tid * 8);
        async_load16(Bt + (long)(n0 + srow) * ldb + k0 + scol,
                     (unsigned short*)Bs[bsel] + tid * 8);
    };

    stage(0, 0);
    __syncthreads();
    int cur = 0;

    for (int k0 = 0; k0 < Kdim; k0 += BK) {
        if (k0 + BK < Kdim) stage(k0 + BK, cur ^ 1);

        bf16x8 af[4], bfv[2];
#pragma unroll
        for (int i = 0; i < 4; i++)
            af[i] = *reinterpret_cast<const bf16x8*>(
                &As[cur][(wr*64 + i*16 + lrow) * BK + quad * 8]);
#pragma unroll
        for (int j = 0; j < 2; j++)
            bfv[j] = *reinterpret_cast<const bf16x8*>(
                &Bs[cur][(wc*32 + j*16 + lrow) * BK + quad * 8]);
#pragma unroll
        for (int i = 0; i < 4; i++)
#pragma unroll
            for (int j = 0; j < 2; j++)
                acc[i][j] = __builtin_amdgcn_mfma_f32_16x16x32_bf16(
                    af[i], bfv[j], acc[i][j], 0, 0, 0);

        __syncthreads();
        cur ^= 1;
    }

#pragma unroll
    for (int i = 0; i < 4; i++)
#pragma unroll
        for (int j = 0; j < 2; j++)
#pragma unroll
            for (int r = 0; r < 4; r++) {
                int row = m0 + wr*64 + i*16 + quad*4 + r;
                int col = n0 + wc*32 + j*16 + lrow;
                float v = acc[i][j][r];
                if (bias) v += bias[col];
                if (gelu_flag) v = 0.5f * v * (1.0f + erff(v * 0.70710678118654752f));
                Cb[(long)row * ldc + col] = f2bf(v);
            }
}

// ------- gemm_bt64: 64x64 tile, NOW BK=128 (was 64). Same dbuf+drain
// schedule, XOR-swizzled LDS (2-way = free), 512 thr / 8 waves with
// wave = (row-group wr, K-slice sw); each wave runs 8 MFMA/iter (2 slices
// of its K-half); end-merge via 16KB f32 LDS pass. Rationale: per-iteration
// cost is a fixed staging-latency drain (~1075cy vs ~150cy issue; MfmaUtil
// 16%, HBM 15%, schedule variants all null) -> halve the DRAIN COUNT.
// MLP2: 48->24 iters; attn-out: 12->6. LDS 64KB -> 2 blocks/CU x 8 waves
// = 16 waves/CU = what the 32KB version already measures (48% occ).
__global__ __launch_bounds__(512) void gemm_bt64(
    const unsigned short* __restrict__ A, int lda,
    const unsigned short* __restrict__ Bt, int ldb,
    int Kdim,
    const float* __restrict__ bias,
    const unsigned short* __restrict__ res1,
    const float* __restrict__ resf,
    float* __restrict__ Cf,
    unsigned short* __restrict__ Cb,
    int ldc)
{
    constexpr int BK = 128;
    __shared__ __align__(16) unsigned short As[2][64 * BK];
    __shared__ __align__(16) unsigned short Bs[2][64 * BK];

    const int tid = threadIdx.x;      // 0..511
    const int wave = tid >> 6;        // 0..7
    const int lane = tid & 63;
    const int quad = lane >> 4;
    const int lr = lane & 15;
    const int wr = wave >> 1;         // 0..3 : 16-row group
    const int sw = wave & 1;          // 0..1 : K-half

    int bx = blockIdx.x, by = blockIdx.y;
    {   // XCD swizzle (1D)
        int flat = by * gridDim.x + bx;
        int xcd = flat & 7, seq = flat >> 3;
        int ypg = gridDim.y >> 3;
        by = xcd * ypg + seq / gridDim.x;
        bx = seq % gridDim.x;
    }
    const int m0 = by * 64;
    const int n0 = bx * 64;

    f32x4 acc[4];
#pragma unroll
    for (int j = 0; j < 4; j++) acc[j] = (f32x4){0.f, 0.f, 0.f, 0.f};

    // staging: tile is 64 rows x 16 col-chunks (8 bf16 each) = 1024 chunks.
    // thread t covers chunks p = t and t+512 (rows r0 and r0+32, same c0).
    // LDS slot (r,c) holds global chunk (r, c ^ (r&7)); since (r0+32)&7 ==
    // r0&7, the second chunk is the same physical column 32 rows down.
    const int r0 = tid >> 4;            // 0..31
    const int c0 = tid & 15;
    const int cc0 = c0 ^ (r0 & 7);
    const unsigned short* aSrc = A  + (long)(m0 + r0) * lda + cc0 * 8;
    const unsigned short* bSrc = Bt + (long)(n0 + r0) * ldb + cc0 * 8;
    const long aOff2 = (long)32 * lda;
    const long bOff2 = (long)32 * ldb;

    auto stage = [&](int k0, int bsel) {
        async_load16(aSrc + k0,         As[bsel] + tid * 8);
        async_load16(aSrc + k0 + aOff2, As[bsel] + (tid + 512) * 8);
        async_load16(bSrc + k0,         Bs[bsel] + tid * 8);
        async_load16(bSrc + k0 + bOff2, Bs[bsel] + (tid + 512) * 8);
    };

    stage(0, 0);
    __syncthreads();
    int cur = 0;

    for (int k0 = 0; k0 < Kdim; k0 += BK) {
        if (k0 + BK < Kdim) stage(k0 + BK, cur ^ 1);

#pragma unroll
        for (int u = 0; u < 2; u++) {
            const int g = (sw * 2 + u) * 4 + quad;     // col-chunk 0..15
            const int arow = wr * 16 + lr;
            bf16x8 af = *(const bf16x8*)&As[cur][(arow * 16 + (g ^ (lr & 7))) * 8];
#pragma unroll
            for (int j = 0; j < 4; j++) {
                int brow = j * 16 + lr;
                bf16x8 bv = *(const bf16x8*)&Bs[cur][(brow * 16 + (g ^ (lr & 7))) * 8];
                acc[j] = __builtin_amdgcn_mfma_f32_16x16x32_bf16(af, bv, acc[j], 0, 0, 0);
            }
        }
        __syncthreads();
        cur ^= 1;
    }

    // merge the two sw partials through LDS (As retired; 64*64 f32 = 16KB
    // fits in As[2][64*128] ushort = 32KB). Final loop barrier above
    // guarantees all LDS reads are done before the overwrite.
    float* mbuf = (float*)As;
    if (sw == 1) {
#pragma unroll
        for (int j = 0; j < 4; j++)
#pragma unroll
            for (int r = 0; r < 4; r++)
                mbuf[(wr * 16 + quad * 4 + r) * 64 + j * 16 + lr] = acc[j][r];
    }
    __syncthreads();
    if (sw == 0) {
#pragma unroll
        for (int j = 0; j < 4; j++)
#pragma unroll
            for (int r = 0; r < 4; r++) {
                int lrow_o = wr * 16 + quad * 4 + r;
                int row = m0 + lrow_o;
                int col = n0 + j * 16 + lr;
                float v = acc[j][r] + mbuf[lrow_o * 64 + j * 16 + lr];
                if (bias) v += bias[col];
                long idx = (long)row * ldc + col;
                if (res1) v += bf2f(res1[idx]);
                if (resf) v += resf[idx];
                if (Cf) Cf[idx] = v;
                else    Cb[idx] = f2bf(v);
            }
    }
}

extern "C" void kernel_launch(void* const* d_in, const int* in_sizes, int n_in,
                              void* d_out, int out_size, void* d_ws, size_t ws_size,
                              hipStream_t stream)
{
    int ix = -1, iwqkv = -1, iwout = -1, iw1 = -1, iw2 = -1, ib1 = -1;
    int v768[8]; int nv = 0;
    for (int i = 0; i < n_in; i++) {
        int s = in_sizes[i];
        if      (s == ROWS*EMBED)        ix = i;
        else if (s == EMBED*3*EMBED)     iwqkv = i;
        else if (s == EMBED*EMBED)       iwout = i;
        else if (s == EMBED*MLP_DIM)     { if (iw1 < 0) iw1 = i; else iw2 = i; }
        else if (s == MLP_DIM)           ib1 = i;
        else if (s == EMBED && nv < 8)   v768[nv++] = i;
    }
    if (n_in != 12 || ix < 0 || iwqkv < 0 || iwout < 0 || iw1 < 0 || iw2 < 0 ||
        ib1 < 0 || nv != 6)
        return;

    const float* x    = (const float*)d_in[ix];
    const float* wqkv = (const float*)d_in[iwqkv];
    const float* wout = (const float*)d_in[iwout];
    const float* w1   = (const float*)d_in[iw1];
    const float* w2   = (const float*)d_in[iw2];
    const float* b1   = (const float*)d_in[ib1];
    float* out = (float*)d_out;

    char* ws = (char*)d_ws;
    size_t off = 0;
    auto alloc = [&](size_t bytes) -> char* {
        char* p = ws + off;
        off += (bytes + 255) & ~(size_t)255;
        return p;
    };
    unsigned short* h_bf  = (unsigned short*)alloc((size_t)ROWS * EMBED * 2);
    unsigned short* qkv   = (unsigned short*)alloc((size_t)ROWS * 3 * EMBED * 2);
    unsigned short* vT    = (unsigned short*)alloc((size_t)BATCH * HEADS * HDIM * SEQ * 2);
    unsigned short* attn  = (unsigned short*)alloc((size_t)ROWS * EMBED * 2);
    float*          x2f   = (float*)alloc((size_t)ROWS * EMBED * 4);
    unsigned short* wqkvT = (unsigned short*)alloc((size_t)3 * EMBED * EMBED * 2);
    unsigned short* woutT = (unsigned short*)alloc((size_t)EMBED * EMBED * 2);
    unsigned short* w1T   = (unsigned short*)alloc((size_t)MLP_DIM * EMBED * 2);
    unsigned short* w2T   = (unsigned short*)alloc((size_t)EMBED * MLP_DIM * 2);
    unsigned short* h2    = (unsigned short*)alloc((size_t)ROWS * EMBED * 2);
    float* vecs           = (float*)alloc((size_t)(6 * EMBED) * 4);
    if (off > ws_size) return;

    float* ln1g_f = vecs;
    float* ln1b_f = vecs + EMBED;
    float* bout_f = vecs + 2 * EMBED;
    float* ln2g_f = vecs + 3 * EMBED;
    float* ln2b_f = vecs + 4 * EMBED;
    float* b2_f   = vecs + 5 * EMBED;
    unsigned short* u = qkv;   // qkv dead after flash attention; u = [4096,3072]

    sort_vecs<<<1, 768, 0, stream>>>(
        (const float*)d_in[v768[0]], (const float*)d_in[v768[1]],
        (const float*)d_in[v768[2]], (const float*)d_in[v768[3]],
        (const float*)d_in[v768[4]], (const float*)d_in[v768[5]],
        ln1g_f, ln1b_f, bout_f, ln2g_f, ln2b_f, b2_f);

    dim3 tb(32, 8);
    transpose_weights<<<6912, tb, 0, stream>>>(wqkv, wout, w1, w2,
                                               wqkvT, woutT, w1T, w2T);

    ln_kernel<<<ROWS, 256, 0, stream>>>(x, ln1g_f, ln1b_f, h_bf);

    // qkv = h @ w_qkv  [4096 x 2304]
    gemm_bt0<<<dim3(3*EMBED/128, ROWS/128), 512, 0, stream>>>(
        h_bf, EMBED, wqkvT, EMBED, EMBED, nullptr, qkv, 3*EMBED, 0);

    // vT[b,h,d,n] = V
    transpose_any<<<dim3(HDIM/32, SEQ/32, BATCH*HEADS), tb, 0, stream>>>(
        qkv + 2*EMBED, vT, 3*EMBED, SEQ,
        (long)SEQ*3*EMBED, (long)HDIM,
        (long)HEADS*HDIM*SEQ, (long)HDIM*SEQ, HEADS, 0);

    // fused attention (max-free online softmax)
    flash_attn<<<dim3(SEQ/64, BATCH*HEADS), 256, 0, stream>>>(qkv, vT, attn);

    // x2 = attn @ w_out + b_out + x + h   (fp32 out)
    gemm_bt64<<<dim3(EMBED/64, ROWS/64), 512, 0, stream>>>(
        attn, EMBED, woutT, EMBED, EMBED,
        bout_f, h_bf, x, x2f, nullptr, EMBED);

    ln_kernel<<<ROWS, 256, 0, stream>>>(x2f, ln2g_f, ln2b_f, h2);

    // u = gelu(h2 @ w1 + b1)
    gemm_bt0<<<dim3(MLP_DIM/128, ROWS/128), 512, 0, stream>>>(
        h2, EMBED, w1T, EMBED, EMBED, b1, u, MLP_DIM, 1);

    // out = u @ w2 + b2 + x2   (f32 out)
    gemm_bt64<<<dim3(EMBED/64, ROWS/64), 512, 0, stream>>>(
        u, MLP_DIM, w2T, MLP_DIM, MLP_DIM,
        b2_f, nullptr, x2f, out, nullptr, EMBED);
}

// Round 12
// 272.492 us; speedup vs baseline: 1.1240x; 1.1240x over previous
//
#include <hip/hip_runtime.h>

#define EMBED 768
#define HEADS 12
#define HDIM 64
#define MLP_DIM 3072
#define BATCH 4
#define SEQ 1024
#define ROWS (BATCH*SEQ)
#define LN_EPS 1e-5f

typedef __bf16 bf16x8 __attribute__((ext_vector_type(8)));
typedef float f32x4 __attribute__((ext_vector_type(4)));

__device__ __forceinline__ float bf2f(unsigned short h) {
    unsigned u = ((unsigned)h) << 16;
    return __builtin_bit_cast(float, u);
}
__device__ __forceinline__ unsigned short f2bf(float f) {
    unsigned u = __builtin_bit_cast(unsigned, f);
    unsigned r = (u + 0x7fffu + ((u >> 16) & 1u)) >> 16;
    return (unsigned short)r;
}

// async global->LDS, 16B per lane (wave-uniform base + lane*16 contract).
__device__ __forceinline__ void async_load16(const unsigned short* g, unsigned short* l) {
    __builtin_amdgcn_global_load_lds(
        (const __attribute__((address_space(1))) unsigned int*)g,
        (__attribute__((address_space(3))) unsigned int*)l,
        16, 0, 0);
}

// ---- classify the six 768-vectors by VALUE and copy to canonical slots ----
__global__ void sort_vecs(const float* a0, const float* a1, const float* a2,
                          const float* a3, const float* a4, const float* a5,
                          float* g1, float* be1, float* bo,
                          float* g2, float* be2, float* bb2)
{
    const float* src[6] = {a0, a1, a2, a3, a4, a5};
    float* gdst[2] = {g1, g2};
    float* bdst[4] = {be1, bo, be2, bb2};
    float* dst[6];
    int gi = 0, bi = 0;
    for (int t = 0; t < 6; t++) {
        bool ones = (src[t][0] == 1.0f);
        if (ones) dst[t] = (gi < 2) ? gdst[gi++] : bdst[bi++];
        else      dst[t] = (bi < 4) ? bdst[bi++] : gdst[gi++];
    }
    int t = threadIdx.x;   // 768 threads
    for (int k = 0; k < 6; k++) dst[k][t] = src[k][t];
}

// ---- all 4 weight transposes (f32 -> bf16 [N,K]) in ONE launch -------------
__global__ void transpose_weights(const float* __restrict__ wqkv,
                                  const float* __restrict__ wout,
                                  const float* __restrict__ w1,
                                  const float* __restrict__ w2,
                                  unsigned short* __restrict__ wqkvT,
                                  unsigned short* __restrict__ woutT,
                                  unsigned short* __restrict__ w1T,
                                  unsigned short* __restrict__ w2T)
{
    __shared__ unsigned short t[32][33];
    int fb = blockIdx.x;
    const float* src; unsigned short* dst; int gx, ild, old;
    if (fb < 1728)      { src = wqkv; dst = wqkvT; gx = 72; ild = 2304; old = 768; }
    else if (fb < 2304) { fb -= 1728; src = wout; dst = woutT; gx = 24; ild = 768;  old = 768; }
    else if (fb < 4608) { fb -= 2304; src = w1;   dst = w1T;   gx = 96; ild = 3072; old = 768; }
    else                { fb -= 4608; src = w2;   dst = w2T;   gx = 24; ild = 768;  old = 3072; }
    const int j0 = (fb % gx) * 32, i0 = (fb / gx) * 32;
#pragma unroll
    for (int r = 0; r < 4; r++)
        t[threadIdx.y + r*8][threadIdx.x] =
            f2bf(src[(long)(i0 + threadIdx.y + r*8) * ild + (j0 + threadIdx.x)]);
    __syncthreads();
#pragma unroll
    for (int r = 0; r < 4; r++)
        dst[(long)(j0 + threadIdx.y + r*8) * old + (i0 + threadIdx.x)] =
            t[threadIdx.x][threadIdx.y + r*8];
}

// ---- tiled transpose (bf16 path, used for vT) ------------------------------
__global__ void transpose_any(const void* __restrict__ in,
                              unsigned short* __restrict__ out,
                              int ild, int old,
                              long in_zo, long in_zi, long out_zo, long out_zi,
                              int zdiv, int in_is_f32)
{
    __shared__ unsigned short t[32][33];
    const int z = blockIdx.z;
    const long ib = (long)(z / zdiv) * in_zo  + (long)(z % zdiv) * in_zi;
    const long ob = (long)(z / zdiv) * out_zo + (long)(z % zdiv) * out_zi;
    const int j0 = blockIdx.x * 32, i0 = blockIdx.y * 32;
#pragma unroll
    for (int r = 0; r < 4; r++) {
        long idx = ib + (long)(i0 + threadIdx.y + r*8) * ild + (j0 + threadIdx.x);
        t[threadIdx.y + r*8][threadIdx.x] =
            in_is_f32 ? f2bf(((const float*)in)[idx]) : ((const unsigned short*)in)[idx];
    }
    __syncthreads();
#pragma unroll
    for (int r = 0; r < 4; r++)
        out[ob + (long)(j0 + threadIdx.y + r*8) * old + (i0 + threadIdx.x)] =
            t[threadIdx.x][threadIdx.y + r*8];
}

// ---------------- LayerNorm: f32 in, f32 gamma/beta -> bf16 out -------------
__global__ void ln_kernel(const float* __restrict__ xin,
                          const float* __restrict__ g,
                          const float* __restrict__ b,
                          unsigned short* __restrict__ out)
{
    const int row = blockIdx.x;
    const int tid = threadIdx.x;
    const long base = (long)row * EMBED;
    float v[3];
#pragma unroll
    for (int i = 0; i < 3; i++) v[i] = xin[base + tid + i * 256];
    float s = v[0] + v[1] + v[2];
    float s2 = v[0]*v[0] + v[1]*v[1] + v[2]*v[2];
    for (int off = 32; off; off >>= 1) { s += __shfl_down(s, off); s2 += __shfl_down(s2, off); }
    __shared__ float ps[4], ps2[4];
    int w = tid >> 6, l = tid & 63;
    if (l == 0) { ps[w] = s; ps2[w] = s2; }
    __syncthreads();
    float ts  = ps[0] + ps[1] + ps[2] + ps[3];
    float ts2 = ps2[0] + ps2[1] + ps2[2] + ps2[3];
    float mu = ts * (1.0f / EMBED);
    float var = ts2 * (1.0f / EMBED) - mu * mu;
    float rs = rsqrtf(var + LN_EPS);
#pragma unroll
    for (int i = 0; i < 3; i++) {
        int c = tid + i * 256;
        out[base + c] = f2bf((v[i] - mu) * rs * g[c] + b[c]);
    }
}

// --------- flash attention v6: swizzled LDS + MAX-FREE softmax --------------
__global__ __launch_bounds__(256) void flash_attn(
    const unsigned short* __restrict__ qkv,
    const unsigned short* __restrict__ vT,
    unsigned short* __restrict__ attn)
{
    __shared__ __align__(16) unsigned short QPs[64 * 64];     // Q staging, then P
    __shared__ __align__(16) unsigned short Ks[2][64 * 64];
    __shared__ __align__(16) unsigned short Vs[2][64 * 64];

    const int tid = threadIdx.x;
    const int wave = tid >> 6, lane = tid & 63;
    const int quad = lane >> 4, lr = lane & 15;
    const int q0 = blockIdx.x * 64;
    const int bh = blockIdx.y;
    const int b = bh / HEADS, h = bh % HEADS;

    const unsigned short* qb = qkv + (size_t)b * SEQ * 3 * EMBED + h * HDIM;
    const unsigned short* kb = qb + EMBED;
    const unsigned short* vb = vT + (size_t)bh * HDIM * SEQ;

#pragma unroll
    for (int cb = 0; cb < 512; cb += 256) {
        int p = cb + tid, r = p >> 3, cc = (p & 7) ^ (r & 7);
        async_load16(qb + (long)(q0 + r) * (3 * EMBED) + cc * 8, QPs + p * 8);
        async_load16(kb + (long)r * (3 * EMBED) + cc * 8, Ks[0] + p * 8);
        async_load16(vb + (long)r * SEQ + cc * 8, Vs[0] + p * 8);
    }
    __syncthreads();

    bf16x8 aq[2];
#pragma unroll
    for (int s = 0; s < 2; s++) {
        int row = wave * 16 + lr;
        aq[s] = *(const bf16x8*)&QPs[(row * 8 + ((s * 4 + quad) ^ (row & 7))) * 8];
    }

    f32x4 oacc[4];
#pragma unroll
    for (int j = 0; j < 4; j++) oacc[j] = (f32x4){0.f, 0.f, 0.f, 0.f};
    float lpart[4] = {0.f, 0.f, 0.f, 0.f};

    int cur = 0;
    for (int t = 0; t < SEQ / 64; t++) {
        bool pf = (t + 1 < SEQ / 64);
        if (pf) {
            int kv0 = (t + 1) * 64;
#pragma unroll
            for (int cb = 0; cb < 512; cb += 256) {
                int p = cb + tid, r = p >> 3, cc = (p & 7) ^ (r & 7);
                async_load16(kb + (long)(kv0 + r) * (3 * EMBED) + cc * 8, Ks[cur ^ 1] + p * 8);
                async_load16(vb + (long)r * SEQ + kv0 + cc * 8, Vs[cur ^ 1] + p * 8);
            }
        }
        f32x4 sacc[4];
#pragma unroll
        for (int j = 0; j < 4; j++) sacc[j] = (f32x4){0.f, 0.f, 0.f, 0.f};
#pragma unroll
        for (int s = 0; s < 2; s++)
#pragma unroll
            for (int j = 0; j < 4; j++) {
                int row = j * 16 + lr;
                bf16x8 bk = *(const bf16x8*)&Ks[cur][(row * 8 + ((s * 4 + quad) ^ (lr & 7))) * 8];
                sacc[j] = __builtin_amdgcn_mfma_f32_16x16x32_bf16(aq[s], bk, sacc[j], 0, 0, 0);
            }
#pragma unroll
        for (int j = 0; j < 4; j++)
#pragma unroll
            for (int r = 0; r < 4; r++) {
                float e = __expf(sacc[j][r] * 0.125f);
                lpart[r] += e;
                int row = wave * 16 + quad * 4 + r;
                int cc = (2 * j + (lr >> 3)) ^ (row & 7);
                QPs[(row * 8 + cc) * 8 + (lr & 7)] = f2bf(e);
            }
#pragma unroll
        for (int s = 0; s < 2; s++) {
            int prow = wave * 16 + lr;
            bf16x8 ap = *(const bf16x8*)&QPs[(prow * 8 + ((s * 4 + quad) ^ (prow & 7))) * 8];
#pragma unroll
            for (int j = 0; j < 4; j++) {
                int vrow = j * 16 + lr;
                bf16x8 bv = *(const bf16x8*)&Vs[cur][(vrow * 8 + ((s * 4 + quad) ^ (lr & 7))) * 8];
                oacc[j] = __builtin_amdgcn_mfma_f32_16x16x32_bf16(ap, bv, oacc[j], 0, 0, 0);
            }
        }
        __syncthreads();
        cur ^= 1;
    }
#pragma unroll
    for (int off = 1; off < 16; off <<= 1)
#pragma unroll
        for (int r = 0; r < 4; r++) lpart[r] += __shfl_xor(lpart[r], off);
#pragma unroll
    for (int j = 0; j < 4; j++)
#pragma unroll
        for (int r = 0; r < 4; r++) {
            int row = q0 + wave * 16 + quad * 4 + r;
            attn[(size_t)(b * SEQ + row) * EMBED + h * HDIM + j * 16 + lr] =
                f2bf(oacc[j][r] / lpart[r]);
        }
}

// ------- gemm_bt0: session-best config. 128x128, BK=32, linear LDS, dbuf,
// drain barrier, 512 thr / 8 waves (R7 occupancy win), 2D XCD swizzle
// (R10 L2-footprint win: 4y x 2x -> per-XCD A+B panels fit the 4MB L2).
__global__ __launch_bounds__(512) void gemm_bt0(
    const unsigned short* __restrict__ A, int lda,
    const unsigned short* __restrict__ Bt, int ldb,
    int Kdim,
    const float* __restrict__ bias,
    unsigned short* __restrict__ Cb,
    int ldc, int gelu_flag)
{
    constexpr int BK = 32;
    __shared__ __align__(16) unsigned short As[2][128 * BK];
    __shared__ __align__(16) unsigned short Bs[2][128 * BK];

    const int tid = threadIdx.x;      // 0..511
    const int wave = tid >> 6;        // 0..7
    const int lane = tid & 63;
    const int quad = lane >> 4;
    const int lrow = lane & 15;
    const int wr = wave >> 2;         // 0..1 : M 64-half
    const int wc = wave & 3;          // 0..3 : N 32-quarter

    int bx = blockIdx.x, by = blockIdx.y;
    {   // 2D XCD swizzle: 4 y-groups x 2 x-groups of XCDs
        int flat = by * gridDim.x + bx;
        int xcd = flat & 7, seq = flat >> 3;
        int gxh = gridDim.x >> 1;   // region width  (x)
        int gyq = gridDim.y >> 2;   // region height (y)
        by = (xcd & 3) * gyq + seq / gxh;
        bx = (xcd >> 2) * gxh + seq % gxh;
    }
    const int m0 = by * 128;
    const int n0 = bx * 128;

    f32x4 acc[4][2];
#pragma unroll
    for (int i = 0; i < 4; i++)
#pragma unroll
        for (int j = 0; j < 2; j++) acc[i][j] = (f32x4){0.f, 0.f, 0.f, 0.f};

    const int srow = tid >> 2;
    const int scol = (tid & 3) * 8;

    auto stage = [&](int k0, int bsel) {
        async_load16(A  + (long)(m0 + srow) * lda + k0 + scol,
                     (unsigned short*)As[bsel] + tid * 8);
        async_load16(Bt + (long)(n0 + srow) * ldb + k0 + scol,
                     (unsigned short*)Bs[bsel] + tid * 8);
    };

    stage(0, 0);
    __syncthreads();
    int cur = 0;

    for (int k0 = 0; k0 < Kdim; k0 += BK) {
        if (k0 + BK < Kdim) stage(k0 + BK, cur ^ 1);

        bf16x8 af[4], bfv[2];
#pragma unroll
        for (int i = 0; i < 4; i++)
            af[i] = *reinterpret_cast<const bf16x8*>(
                &As[cur][(wr*64 + i*16 + lrow) * BK + quad * 8]);
#pragma unroll
        for (int j = 0; j < 2; j++)
            bfv[j] = *reinterpret_cast<const bf16x8*>(
                &Bs[cur][(wc*32 + j*16 + lrow) * BK + quad * 8]);
#pragma unroll
        for (int i = 0; i < 4; i++)
#pragma unroll
            for (int j = 0; j < 2; j++)
                acc[i][j] = __builtin_amdgcn_mfma_f32_16x16x32_bf16(
                    af[i], bfv[j], acc[i][j], 0, 0, 0);

        __syncthreads();
        cur ^= 1;
    }

#pragma unroll
    for (int i = 0; i < 4; i++)
#pragma unroll
        for (int j = 0; j < 2; j++)
#pragma unroll
            for (int r = 0; r < 4; r++) {
                int row = m0 + wr*64 + i*16 + quad*4 + r;
                int col = n0 + wc*32 + j*16 + lrow;
                float v = acc[i][j][r];
                if (bias) v += bias[col];
                if (gelu_flag) v = 0.5f * v * (1.0f + erff(v * 0.70710678118654752f));
                Cb[(long)row * ldc + col] = f2bf(v);
            }
}

// ------- gemm_bt64: session-best config. 64x64 tile, BK=64, XOR-swizzled
// LDS, dbuf drain, 512 threads / 8 waves: wave = (row-group wr, K-slice sw);
// end-merge via 16KB f32 LDS pass. (BK=128 variant regressed: broken read
// swizzle -> 6.1M conflicts + 64KB LDS halved occupancy. Reverted.)
__global__ __launch_bounds__(512) void gemm_bt64(
    const unsigned short* __restrict__ A, int lda,
    const unsigned short* __restrict__ Bt, int ldb,
    int Kdim,
    const float* __restrict__ bias,
    const unsigned short* __restrict__ res1,
    const float* __restrict__ resf,
    float* __restrict__ Cf,
    unsigned short* __restrict__ Cb,
    int ldc)
{
    __shared__ __align__(16) unsigned short As[2][64 * 64];
    __shared__ __align__(16) unsigned short Bs[2][64 * 64];

    const int tid = threadIdx.x;      // 0..511
    const int wave = tid >> 6;        // 0..7
    const int lane = tid & 63;
    const int quad = lane >> 4;
    const int lr = lane & 15;
    const int wr = wave >> 1;         // 0..3 : 16-row group
    const int sw = wave & 1;          // 0..1 : K-inner slice

    int bx = blockIdx.x, by = blockIdx.y;
    {   // XCD swizzle
        int flat = by * gridDim.x + bx;
        int xcd = flat & 7, seq = flat >> 3;
        int ypg = gridDim.y >> 3;
        by = xcd * ypg + seq / gridDim.x;
        bx = seq % gridDim.x;
    }
    const int m0 = by * 64;
    const int n0 = bx * 64;

    f32x4 acc[4];
#pragma unroll
    for (int j = 0; j < 4; j++) acc[j] = (f32x4){0.f, 0.f, 0.f, 0.f};

    // swizzled staging: chunk (r,c) of the 64x64 tile at slot r*8 + (c^(r&7)).
    // 512 threads: each stages 1 A chunk + 1 B chunk per K-tile.
    auto stage = [&](int k0, unsigned short* Ad, unsigned short* Bd) {
        int p = tid, r = p >> 3, cc = (p & 7) ^ (r & 7);
        async_load16(A + (long)(m0 + r) * lda + k0 + cc * 8, Ad + p * 8);
        async_load16(Bt + (long)(n0 + r) * ldb + k0 + cc * 8, Bd + p * 8);
    };

    stage(0, As[0], Bs[0]);
    __syncthreads();
    int cur = 0;

    for (int k0 = 0; k0 < Kdim; k0 += 64) {
        if (k0 + 64 < Kdim) stage(k0 + 64, As[cur ^ 1], Bs[cur ^ 1]);

        int arow = wr * 16 + lr;
        bf16x8 af = *(const bf16x8*)&As[cur][(arow * 8 + ((sw * 4 + quad) ^ (lr & 7))) * 8];
#pragma unroll
        for (int j = 0; j < 4; j++) {
            int brow = j * 16 + lr;
            bf16x8 bv = *(const bf16x8*)&Bs[cur][(brow * 8 + ((sw * 4 + quad) ^ (lr & 7))) * 8];
            acc[j] = __builtin_amdgcn_mfma_f32_16x16x32_bf16(af, bv, acc[j], 0, 0, 0);
        }
        __syncthreads();
        cur ^= 1;
    }

    // merge the two sw partials through LDS (As retired; 64*64 f32 = 16KB
    // exactly overlays As[2][64*64] ushort). Final loop barrier above
    // guarantees all LDS reads are done before the overwrite.
    float* mbuf = (float*)As;
    if (sw == 1) {
#pragma unroll
        for (int j = 0; j < 4; j++)
#pragma unroll
            for (int r = 0; r < 4; r++)
                mbuf[(wr * 16 + quad * 4 + r) * 64 + j * 16 + lr] = acc[j][r];
    }
    __syncthreads();
    if (sw == 0) {
#pragma unroll
        for (int j = 0; j < 4; j++)
#pragma unroll
            for (int r = 0; r < 4; r++) {
                int lrow_o = wr * 16 + quad * 4 + r;
                int row = m0 + lrow_o;
                int col = n0 + j * 16 + lr;
                float v = acc[j][r] + mbuf[lrow_o * 64 + j * 16 + lr];
                if (bias) v += bias[col];
                long idx = (long)row * ldc + col;
                if (res1) v += bf2f(res1[idx]);
                if (resf) v += resf[idx];
                if (Cf) Cf[idx] = v;
                else    Cb[idx] = f2bf(v);
            }
    }
}

extern "C" void kernel_launch(void* const* d_in, const int* in_sizes, int n_in,
                              void* d_out, int out_size, void* d_ws, size_t ws_size,
                              hipStream_t stream)
{
    int ix = -1, iwqkv = -1, iwout = -1, iw1 = -1, iw2 = -1, ib1 = -1;
    int v768[8]; int nv = 0;
    for (int i = 0; i < n_in; i++) {
        int s = in_sizes[i];
        if      (s == ROWS*EMBED)        ix = i;
        else if (s == EMBED*3*EMBED)     iwqkv = i;
        else if (s == EMBED*EMBED)       iwout = i;
        else if (s == EMBED*MLP_DIM)     { if (iw1 < 0) iw1 = i; else iw2 = i; }
        else if (s == MLP_DIM)           ib1 = i;
        else if (s == EMBED && nv < 8)   v768[nv++] = i;
    }
    if (n_in != 12 || ix < 0 || iwqkv < 0 || iwout < 0 || iw1 < 0 || iw2 < 0 ||
        ib1 < 0 || nv != 6)
        return;

    const float* x    = (const float*)d_in[ix];
    const float* wqkv = (const float*)d_in[iwqkv];
    const float* wout = (const float*)d_in[iwout];
    const float* w1   = (const float*)d_in[iw1];
    const float* w2   = (const float*)d_in[iw2];
    const float* b1   = (const float*)d_in[ib1];
    float* out = (float*)d_out;

    char* ws = (char*)d_ws;
    size_t off = 0;
    auto alloc = [&](size_t bytes) -> char* {
        char* p = ws + off;
        off += (bytes + 255) & ~(size_t)255;
        return p;
    };
    unsigned short* h_bf  = (unsigned short*)alloc((size_t)ROWS * EMBED * 2);
    unsigned short* qkv   = (unsigned short*)alloc((size_t)ROWS * 3 * EMBED * 2);
    unsigned short* vT    = (unsigned short*)alloc((size_t)BATCH * HEADS * HDIM * SEQ * 2);
    unsigned short* attn  = (unsigned short*)alloc((size_t)ROWS * EMBED * 2);
    float*          x2f   = (float*)alloc((size_t)ROWS * EMBED * 4);
    unsigned short* wqkvT = (unsigned short*)alloc((size_t)3 * EMBED * EMBED * 2);
    unsigned short* woutT = (unsigned short*)alloc((size_t)EMBED * EMBED * 2);
    unsigned short* w1T   = (unsigned short*)alloc((size_t)MLP_DIM * EMBED * 2);
    unsigned short* w2T   = (unsigned short*)alloc((size_t)EMBED * MLP_DIM * 2);
    unsigned short* h2    = (unsigned short*)alloc((size_t)ROWS * EMBED * 2);
    float* vecs           = (float*)alloc((size_t)(6 * EMBED) * 4);
    if (off > ws_size) return;

    float* ln1g_f = vecs;
    float* ln1b_f = vecs + EMBED;
    float* bout_f = vecs + 2 * EMBED;
    float* ln2g_f = vecs + 3 * EMBED;
    float* ln2b_f = vecs + 4 * EMBED;
    float* b2_f   = vecs + 5 * EMBED;
    unsigned short* u = qkv;   // qkv dead after flash attention; u = [4096,3072]

    sort_vecs<<<1, 768, 0, stream>>>(
        (const float*)d_in[v768[0]], (const float*)d_in[v768[1]],
        (const float*)d_in[v768[2]], (const float*)d_in[v768[3]],
        (const float*)d_in[v768[4]], (const float*)d_in[v768[5]],
        ln1g_f, ln1b_f, bout_f, ln2g_f, ln2b_f, b2_f);

    dim3 tb(32, 8);
    transpose_weights<<<6912, tb, 0, stream>>>(wqkv, wout, w1, w2,
                                               wqkvT, woutT, w1T, w2T);

    ln_kernel<<<ROWS, 256, 0, stream>>>(x, ln1g_f, ln1b_f, h_bf);

    // qkv = h @ w_qkv  [4096 x 2304]
    gemm_bt0<<<dim3(3*EMBED/128, ROWS/128), 512, 0, stream>>>(
        h_bf, EMBED, wqkvT, EMBED, EMBED, nullptr, qkv, 3*EMBED, 0);

    // vT[b,h,d,n] = V
    transpose_any<<<dim3(HDIM/32, SEQ/32, BATCH*HEADS), tb, 0, stream>>>(
        qkv + 2*EMBED, vT, 3*EMBED, SEQ,
        (long)SEQ*3*EMBED, (long)HDIM,
        (long)HEADS*HDIM*SEQ, (long)HDIM*SEQ, HEADS, 0);

    // fused attention (max-free online softmax)
    flash_attn<<<dim3(SEQ/64, BATCH*HEADS), 256, 0, stream>>>(qkv, vT, attn);

    // x2 = attn @ w_out + b_out + x + h   (fp32 out)
    gemm_bt64<<<dim3(EMBED/64, ROWS/64), 512, 0, stream>>>(
        attn, EMBED, woutT, EMBED, EMBED,
        bout_f, h_bf, x, x2f, nullptr, EMBED);

    ln_kernel<<<ROWS, 256, 0, stream>>>(x2f, ln2g_f, ln2b_f, h2);

    // u = gelu(h2 @ w1 + b1)
    gemm_bt0<<<dim3(MLP_DIM/128, ROWS/128), 512, 0, stream>>>(
        h2, EMBED, w1T, EMBED, EMBED, b1, u, MLP_DIM, 1);

    // out = u @ w2 + b2 + x2   (f32 out)
    gemm_bt64<<<dim3(EMBED/64, ROWS/64), 512, 0, stream>>>(
        u, MLP_DIM, w2T, MLP_DIM, MLP_DIM,
        b2_f, nullptr, x2f, out, nullptr, EMBED);
}